// Round 10
// baseline (4534.455 us; speedup 1.0000x reference)
//
#include <hip/hip_runtime.h>
#include <math.h>

#define NNODES 30000
#define NEDGES 480000
#define NC 32
#define NL 3
#define NH 64
#define NBASIS 8
#define NSPEC 5
#define INV_AVG 0.0625f   // 1 / AVG_NEIGH

typedef _Float16 half2v __attribute__((ext_vector_type(2)));
typedef unsigned int uint32;

__device__ __forceinline__ float silu_f(float x) {
    return x / (1.f + __expf(-x));
}
__device__ __forceinline__ float rdlane(float v, int k) {
    return __uint_as_float(__builtin_amdgcn_readlane(__float_as_uint(v), k));
}
__device__ __forceinline__ half2v u2h(uint32 u) {
    union { uint32 u; half2v h; } x; x.u = u; return x.h;
}
__device__ __forceinline__ uint32 packh2(float a, float b) {
    union { uint32 u; half2v h; } x;
    x.h.x = (_Float16)a; x.h.y = (_Float16)b; return x.u;
}

// wgt tile layout: edge gi -> tile T=gi>>6, el=gi&63.
// half h of edge gi lives at  T*10240 + (h>>3)*512 + el*8 + (h&7).

// ---------------------------------------------------------------- geometry
__global__ void geom_kernel(const float* __restrict__ vec,
                            float* __restrict__ nhat4,   // [E][4]
                            float* __restrict__ rb) {    // [E][8]
    int e = blockIdx.x * blockDim.x + threadIdx.x;
    if (e >= NEDGES) return;
    float vx = vec[3*e+0] * 0.25f;   // vectors / R_MAX
    float vy = vec[3*e+1] * 0.25f;
    float vz = vec[3*e+2] * 0.25f;
    float len = sqrtf(vx*vx + vy*vy + vz*vz);      // scaled length
    float inv = 1.f / fmaxf(len, 1e-9f);
    float4 nh = make_float4(vx*inv, vy*inv, vz*inv, 0.f);
    *(float4*)(nhat4 + (size_t)e*4) = nh;
    float x = len * 0.25f;                         // lengths / R_MAX (again)
    float x3 = x*x*x;
    float x6 = x3*x3;
    float x7 = x6*x;
    float x8 = x7*x;
    float env = (x < 1.f) ? (1.f - 28.f*x6 + 48.f*x7 - 21.f*x8) : 0.f;
    float scale = 0.7071067811865476f * inv * env; // sqrt(2/R_MAX)/max(len,eps)*env
    #pragma unroll
    for (int i = 0; i < NBASIS; ++i) {
        rb[NBASIS*e + i] = scale * sinf((float)(i+1) * 3.14159265358979f * x);
    }
}

// ---------------------------------------------------------------- CSR build
__global__ void count_kernel(const int* __restrict__ receivers, int* __restrict__ deg) {
    int e = blockIdx.x * blockDim.x + threadIdx.x;
    if (e >= NEDGES) return;
    atomicAdd(&deg[receivers[e]], 1);
}

__global__ void scan_kernel(const int* __restrict__ deg, int* __restrict__ rowstart) {
    __shared__ int lsum[256];
    __shared__ int loff[256];
    int t = threadIdx.x;
    int lo = t * 118;
    int hi = min(lo + 118, NNODES);
    int s = 0;
    for (int i = lo; i < hi; ++i) s += deg[i];
    lsum[t] = s;
    __syncthreads();
    if (t == 0) {
        int run = 0;
        for (int i = 0; i < 256; ++i) { loff[i] = run; run += lsum[i]; }
    }
    __syncthreads();
    int run = loff[t];
    for (int i = lo; i < hi; ++i) { rowstart[i] = run; run += deg[i]; }
    if (t == 0) rowstart[NNODES] = NEDGES;
}

__global__ void copy_cursor_kernel(const int* __restrict__ rowstart, int* __restrict__ cursor) {
    int i = blockIdx.x * blockDim.x + threadIdx.x;
    if (i < NNODES) cursor[i] = rowstart[i];
}

__global__ void fill_kernel(const int* __restrict__ receivers,
                            int* __restrict__ cursor, int* __restrict__ edge_order) {
    int e = blockIdx.x * blockDim.x + threadIdx.x;
    if (e >= NEDGES) return;
    int pos = atomicAdd(&cursor[receivers[e]], 1);
    edge_order[pos] = e;
}

// ---------------------------------------------------------------- permute edge data (once)
__global__ void perm_kernel(const int* __restrict__ edge_order,
                            const int* __restrict__ senders,
                            const float* __restrict__ nhat4,
                            const float* __restrict__ rb,
                            float* __restrict__ nh_perm, int* __restrict__ snd_perm,
                            float* __restrict__ rb_perm) {
    int i = blockIdx.x * blockDim.x + threadIdx.x;
    if (i >= NEDGES) return;
    int e = edge_order[i];
    *(float4*)(nh_perm + (size_t)i*4) = *(const float4*)(nhat4 + (size_t)e*4);
    snd_perm[i] = senders[e];
    *(float4*)(rb_perm + (size_t)i*8)     = *(const float4*)(rb + (size_t)e*8);
    *(float4*)(rb_perm + (size_t)i*8 + 4) = *(const float4*)(rb + (size_t)e*8 + 4);
}

// ---------------------------------------------------------------- weight prep (once)
// w1t[l][k][b];  w2p[l][kp][j] = (W2[2kp][j],W2[2kp+1][j]) fp16 pair;
// w3p[l][o][kp] = (W3[2kp][o],W3[2kp+1][o]) fp16 pair
__global__ void prepw_kernel(const float* __restrict__ w1, const float* __restrict__ w2,
                             const float* __restrict__ w3,
                             float* __restrict__ w1t, uint32* __restrict__ w2p,
                             uint32* __restrict__ w3p) {
    int t = blockIdx.x * blockDim.x + threadIdx.x;
    if (t < NL * 64 * 8) {
        int l = t / 512, r = t % 512, k = r >> 3, b = r & 7;
        w1t[t] = w1[l * 512 + b * 64 + k];
    }
    int u = t - NL * 64 * 8;
    if (u >= 0 && u < NL * 32 * 64) {
        int l = u / 2048, r = u % 2048, kp = r >> 6, j = r & 63;
        const float* wl = w2 + l * 4096;
        w2p[u] = packh2(wl[(2*kp) * 64 + j], wl[(2*kp+1) * 64 + j]);
    }
    int v = t - NL * 64 * 8 - NL * 32 * 64;
    if (v >= 0 && v < NL * 160 * 32) {
        int l = v / 5120, r = v % 5120, o = r >> 5, kp = r & 31;
        const float* wl = w3 + l * 10240;
        w3p[v] = packh2(wl[(2*kp) * 160 + o], wl[(2*kp+1) * 160 + o]);
    }
}

// ---------------------------------------------------------------- node init
__global__ void init_kernel(const int* __restrict__ specie,
                            const float* __restrict__ emb,
                            float* __restrict__ s) {
    int t = blockIdx.x * blockDim.x + threadIdx.x;
    if (t >= NNODES * NC) return;
    int n = t >> 5;
    int c = t & 31;
    s[t] = emb[specie[n] * NC + c];
}

// ---------------------------------------------------------------- fused radial MLP
// Thread-per-edge, coalesced rb_perm input. Phase 1: h1 pairs -> dot2 with
// packed W2 into acc[64] (fp32). Pack acc -> h[32] (acc dies -> VGPR drops).
// Phase 2: 160 outputs via dot2 with packed W3; tiled coalesced stores.
__global__ __launch_bounds__(256, 4) void mlpf_kernel(
    const float* __restrict__ rb_perm,     // [E][8] permuted order
    const float* __restrict__ w1t,         // [64][8]
    const uint32* __restrict__ w2p,        // [32][64]
    const uint32* __restrict__ w3p,        // [160][32]
    _Float16* __restrict__ wgt16)          // tiled layout
{
    int i = blockIdx.x * 256 + threadIdx.x;
    if (i >= NEDGES) return;
    float4 ra = *(const float4*)(rb_perm + (size_t)i * 8);
    float4 rv = *(const float4*)(rb_perm + (size_t)i * 8 + 4);

    float acc[NH];
    #pragma unroll
    for (int j = 0; j < NH; ++j) acc[j] = 0.f;

    #pragma unroll 1
    for (int kp = 0; kp < 32; ++kp) {
        const float* wk = w1t + kp * 16;
        float h0, h1v;
        h0 = ra.x * wk[0];
        h0 = fmaf(ra.y, wk[1], h0);
        h0 = fmaf(ra.z, wk[2], h0);
        h0 = fmaf(ra.w, wk[3], h0);
        h0 = fmaf(rv.x, wk[4], h0);
        h0 = fmaf(rv.y, wk[5], h0);
        h0 = fmaf(rv.z, wk[6], h0);
        h0 = fmaf(rv.w, wk[7], h0);
        h1v = ra.x * wk[8];
        h1v = fmaf(ra.y, wk[9],  h1v);
        h1v = fmaf(ra.z, wk[10], h1v);
        h1v = fmaf(ra.w, wk[11], h1v);
        h1v = fmaf(rv.x, wk[12], h1v);
        h1v = fmaf(rv.y, wk[13], h1v);
        h1v = fmaf(rv.z, wk[14], h1v);
        h1v = fmaf(rv.w, wk[15], h1v);
        uint32 hp = packh2(silu_f(h0), silu_f(h1v));
        const uint32* w2k = w2p + kp * 64;
        #pragma unroll
        for (int j = 0; j < NH; ++j)
            acc[j] = __builtin_amdgcn_fdot2(u2h(hp), u2h(w2k[j]), acc[j], false);
    }

    // pack h2 -> 32 uints; acc dies here (register pressure drops)
    uint32 h[32];
    #pragma unroll
    for (int q = 0; q < 32; ++q)
        h[q] = packh2(silu_f(acc[2*q]), silu_f(acc[2*q+1]));

    _Float16* tp = wgt16 + (size_t)(i >> 6) * 10240 + (i & 63) * 8;
    #pragma unroll 1
    for (int ob = 0; ob < 160; ob += 8) {
        float t[8];
        #pragma unroll
        for (int o = 0; o < 8; ++o) {
            const uint32* wr = w3p + (ob + o) * 32;
            float a = 0.f;
            #pragma unroll
            for (int kp = 0; kp < 32; ++kp)
                a = __builtin_amdgcn_fdot2(u2h(h[kp]), u2h(wr[kp]), a, false);
            t[o] = a;
        }
        uint4 pk;
        pk.x = packh2(t[0], t[1]);
        pk.y = packh2(t[2], t[3]);
        pk.z = packh2(t[4], t[5]);
        pk.w = packh2(t[6], t[7]);
        *(uint4*)(tp + (ob >> 3) * 512) = pk;
    }
}

// ---------------------------------------------------------------- gather + TP
// Wave per node; prefetch next edge's snd/nh to break the load->use chain.
__global__ __launch_bounds__(512) void gather_tp_kernel(
    const _Float16* __restrict__ wgt16,   // tiled layout
    const float* __restrict__ nh_perm,    // [E][4]
    const int* __restrict__ snd_perm,     // [E]
    const int* __restrict__ rowstart, const int* __restrict__ deg,
    const float* __restrict__ s_in, const float* __restrict__ v_in,  // v: [N][3][32]
    float* __restrict__ agg_s,      // [N][64]
    float* __restrict__ agg_v)      // [N][96][3]
{
    int lane = threadIdx.x & 63;
    int wid  = threadIdx.x >> 6;
    int n = blockIdx.x * 8 + wid;
    if (n >= NNODES) return;

    int c = lane & 31;
    int half = lane >> 5;
    int off01 = half * 32 + c;

    int o0 = ((off01 >> 3) << 9) + (off01 & 7);            // half index off01
    int o2 = (((128 + c) >> 3) << 9) + (c & 7);            // half index 128+c

    float accS = 0.f;
    float aVa0 = 0.f, aVa1 = 0.f, aVa2 = 0.f;   // half0: path2, half1: path3
    float aVb0 = 0.f, aVb1 = 0.f, aVb2 = 0.f;   // half0: path4, half1: garbage

    int start = rowstart[n];
    int cnt   = deg[n];

    int snd_n = 0;
    float4 nh_n = make_float4(0.f, 0.f, 0.f, 0.f);
    if (cnt > 0) {
        snd_n = snd_perm[start];
        nh_n  = *(const float4*)(nh_perm + (size_t)start * 4);
    }

    for (int i = 0; i < cnt; ++i) {
        int idx = start + i;
        int snd = snd_n;
        float4 nh = nh_n;
        const _Float16* tp = wgt16 + (size_t)(idx >> 6) * 10240 + (idx & 63) * 8;

        float d0  = (float)tp[o0];           // half0: wgt0[c]  half1: wgt1[c]
        float d1  = (float)tp[o0 + 4096];    // half0: wgt2[c]  half1: wgt3[c]
        float d2f = (float)tp[o2];           // wgt4[c] (half1 discards)

        // prefetch next edge's snd/nh (independent of this iteration's chain)
        if (i + 1 < cnt) {
            snd_n = snd_perm[idx + 1];
            nh_n  = *(const float4*)(nh_perm + (size_t)(idx + 1) * 4);
        }

        float su = s_in[(size_t)snd * NC + c];
        float v0 = v_in[(size_t)snd * 96 + c];
        float v1 = v_in[(size_t)snd * 96 + 32 + c];
        float v2 = v_in[(size_t)snd * 96 + 64 + c];
        float ndv = nh.x * v0;
        ndv = fmaf(nh.y, v1, ndv);
        ndv = fmaf(nh.z, v2, ndv);

        float sSel = half ? ndv : su;          // path1 vs path0 multiplier
        accS = fmaf(d0, sSel, accS);
        float scale = half ? d1 : d1 * su;     // path3: w3 ; path2: w2*su
        float f0 = half ? v0 : nh.x;
        float f1 = half ? v1 : nh.y;
        float f2 = half ? v2 : nh.z;
        aVa0 = fmaf(scale, f0, aVa0);
        aVa1 = fmaf(scale, f1, aVa1);
        aVa2 = fmaf(scale, f2, aVa2);
        float m4 = half ? 0.f : d2f;           // path4 only on half0
        aVb0 = fmaf(m4, fmaf(nh.x, ndv, -v0 * (1.f / 3.f)), aVb0);
        aVb1 = fmaf(m4, fmaf(nh.y, ndv, -v1 * (1.f / 3.f)), aVb1);
        aVb2 = fmaf(m4, fmaf(nh.z, ndv, -v2 * (1.f / 3.f)), aVb2);
    }

    agg_s[(size_t)n * 64 + lane] = accS;
    float* av = agg_v + (size_t)n * 288;
    if (half == 0) {
        av[c * 3 + 0] = aVa0; av[c * 3 + 1] = aVa1; av[c * 3 + 2] = aVa2;                      // path2
        av[(64 + c) * 3 + 0] = aVb0; av[(64 + c) * 3 + 1] = aVb1; av[(64 + c) * 3 + 2] = aVb2; // path4
    } else {
        av[(32 + c) * 3 + 0] = aVa0; av[(32 + c) * 3 + 1] = aVa1; av[(32 + c) * 3 + 2] = aVa2; // path3
    }
}

// ---------------------------------------------------------------- fallback gather (Round-2)
__global__ __launch_bounds__(512) void gather_kernel(
    const float* __restrict__ rb, const float* __restrict__ nhat4,
    const int* __restrict__ senders, const int* __restrict__ edge_order,
    const int* __restrict__ rowstart, const int* __restrict__ deg,
    const float* __restrict__ s_in, const float* __restrict__ v_in,
    const float* __restrict__ w1, const float* __restrict__ w2, const float* __restrict__ w3,
    float* __restrict__ agg_s, float* __restrict__ agg_v)
{
    __shared__ float sW2[NH * NH];
    __shared__ float sW3[NH * 160];
    for (int i = threadIdx.x; i < NH * NH;  i += 512) sW2[i] = w2[i];
    for (int i = threadIdx.x; i < NH * 160; i += 512) sW3[i] = w3[i];
    __syncthreads();
    int lane = threadIdx.x & 63;
    int wid  = threadIdx.x >> 6;
    int n = blockIdx.x * 8 + wid;
    if (n >= NNODES) return;
    int c = lane & 31;
    int half = lane >> 5;
    float w1r[8];
    #pragma unroll
    for (int b = 0; b < 8; ++b) w1r[b] = w1[b * NH + lane];
    float accS = 0.f;
    float aVa0 = 0.f, aVa1 = 0.f, aVa2 = 0.f;
    float aVb0 = 0.f, aVb1 = 0.f, aVb2 = 0.f;
    int start = rowstart[n];
    int cnt   = deg[n];
    for (int i = 0; i < cnt; ++i) {
        int e   = edge_order[start + i];
        int snd = senders[e];
        float4 nh  = *(const float4*)(nhat4 + (size_t)e * 4);
        float4 rba = *(const float4*)(rb + (size_t)e * 8);
        float4 rbb = *(const float4*)(rb + (size_t)e * 8 + 4);
        float h1v;
        h1v = rba.x * w1r[0];
        h1v = fmaf(rba.y, w1r[1], h1v);
        h1v = fmaf(rba.z, w1r[2], h1v);
        h1v = fmaf(rba.w, w1r[3], h1v);
        h1v = fmaf(rbb.x, w1r[4], h1v);
        h1v = fmaf(rbb.y, w1r[5], h1v);
        h1v = fmaf(rbb.z, w1r[6], h1v);
        h1v = fmaf(rbb.w, w1r[7], h1v);
        h1v = silu_f(h1v);
        float a0 = 0.f, a1 = 0.f;
        #pragma unroll
        for (int k = 0; k < NH; k += 2) {
            a0 = fmaf(rdlane(h1v, k),     sW2[k * NH + lane],       a0);
            a1 = fmaf(rdlane(h1v, k + 1), sW2[(k + 1) * NH + lane], a1);
        }
        float h2v = silu_f(a0 + a1);
        float d0a = 0.f, d0b = 0.f, d1a = 0.f, d1b = 0.f, d2a = 0.f, d2b = 0.f;
        #pragma unroll
        for (int k = 0; k < NH; k += 2) {
            float hA = rdlane(h2v, k);
            float hB = rdlane(h2v, k + 1);
            d0a = fmaf(hA, sW3[k * 160 + lane],            d0a);
            d1a = fmaf(hA, sW3[k * 160 + 64 + lane],       d1a);
            d2a = fmaf(hA, sW3[k * 160 + 128 + c],         d2a);
            d0b = fmaf(hB, sW3[(k + 1) * 160 + lane],      d0b);
            d1b = fmaf(hB, sW3[(k + 1) * 160 + 64 + lane], d1b);
            d2b = fmaf(hB, sW3[(k + 1) * 160 + 128 + c],   d2b);
        }
        float d0 = d0a + d0b;
        float d1 = d1a + d1b;
        float d2 = d2a + d2b;
        float su = s_in[(size_t)snd * NC + c];
        float v0 = v_in[(size_t)snd * 96 + c];
        float v1 = v_in[(size_t)snd * 96 + 32 + c];
        float v2 = v_in[(size_t)snd * 96 + 64 + c];
        float ndv = nh.x * v0;
        ndv = fmaf(nh.y, v1, ndv);
        ndv = fmaf(nh.z, v2, ndv);
        float sSel = half ? ndv : su;
        accS = fmaf(d0, sSel, accS);
        float scale = half ? d1 : d1 * su;
        float f0 = half ? v0 : nh.x;
        float f1 = half ? v1 : nh.y;
        float f2 = half ? v2 : nh.z;
        aVa0 = fmaf(scale, f0, aVa0);
        aVa1 = fmaf(scale, f1, aVa1);
        aVa2 = fmaf(scale, f2, aVa2);
        float m4 = half ? 0.f : d2;
        aVb0 = fmaf(m4, fmaf(nh.x, ndv, -v0 * (1.f / 3.f)), aVb0);
        aVb1 = fmaf(m4, fmaf(nh.y, ndv, -v1 * (1.f / 3.f)), aVb1);
        aVb2 = fmaf(m4, fmaf(nh.z, ndv, -v2 * (1.f / 3.f)), aVb2);
    }
    agg_s[(size_t)n * 64 + lane] = accS;
    float* av = agg_v + (size_t)n * 288;
    if (half == 0) {
        av[c * 3 + 0] = aVa0; av[c * 3 + 1] = aVa1; av[c * 3 + 2] = aVa2;
        av[(64 + c) * 3 + 0] = aVb0; av[(64 + c) * 3 + 1] = aVb1; av[(64 + c) * 3 + 2] = aVb2;
    } else {
        av[(32 + c) * 3 + 0] = aVa0; av[(32 + c) * 3 + 1] = aVa1; av[(32 + c) * 3 + 2] = aVa2;
    }
}

// ---------------------------------------------------------------- node update (v2)
__global__ __launch_bounds__(256) void node_kernel(
    const int* __restrict__ specie,
    const float* __restrict__ agg_s, const float* __restrict__ agg_v,
    const float* __restrict__ s_in,  const float* __restrict__ v_in,
    const float* __restrict__ wls,   // [64][64]
    const float* __restrict__ wlv,   // [96][32]
    const float* __restrict__ wscs,  // [5][32][64]
    const float* __restrict__ wscv,  // [5][32][32]
    float* __restrict__ s_out, float* __restrict__ v_out)
{
    __shared__ float sAV[4][288];
    __shared__ float sVO[4][96];

    int lane = threadIdx.x & 63;
    int wid  = threadIdx.x >> 6;
    int n = blockIdx.x * 4 + wid;
    if (n >= NNODES) return;
    int sp = specie[n];

    const float* av = agg_v + (size_t)n * 288;
    sAV[wid][lane]       = av[lane];
    sAV[wid][64 + lane]  = av[64 + lane];
    sAV[wid][128 + lane] = av[128 + lane];
    sAV[wid][192 + lane] = av[192 + lane];
    if (lane < 32) sAV[wid][256 + lane] = av[256 + lane];
    const float* vo = v_in + (size_t)n * 96;
    if (lane < 32) {
        sVO[wid][lane]      = vo[lane];
        sVO[wid][32 + lane] = vo[32 + lane];
        sVO[wid][64 + lane] = vo[64 + lane];
    }

    float asv = agg_s[(size_t)n * 64 + lane];
    float sv  = s_in[(size_t)n * 32 + (lane & 31)];

    __syncthreads();

    float sg = 0.f;
    #pragma unroll
    for (int j = 0; j < 64; ++j)
        sg = fmaf(rdlane(asv, j), wls[j * 64 + lane], sg);
    sg *= INV_AVG;
    const float* ws = wscs + (size_t)sp * 32 * 64;
    #pragma unroll
    for (int j = 0; j < 32; ++j)
        sg = fmaf(rdlane(sv, j), ws[j * 64 + lane], sg);
    float act  = silu_f(sg);
    float gate = __shfl(act, (lane & 31) + 32);

    int c = lane & 31;
    int h = lane >> 5;
    float vn1 = 0.f, vn2 = 0.f;
    #pragma unroll
    for (int p = 0; p < 96; ++p) {
        float w = wlv[p * 32 + c];
        vn1 = fmaf(sAV[wid][3 * p + h], w, vn1);
        vn2 = fmaf(sAV[wid][3 * p + 2], w, vn2);
    }
    vn1 *= INV_AVG; vn2 *= INV_AVG;
    const float* wv = wscv + (size_t)sp * 32 * 32;
    #pragma unroll
    for (int j = 0; j < 32; ++j) {
        float w = wv[j * 32 + c];
        vn1 = fmaf(sVO[wid][h * 32 + j], w, vn1);
        vn2 = fmaf(sVO[wid][64 + j],     w, vn2);
    }

    if (lane < 32) s_out[(size_t)n * 32 + lane] = act;
    v_out[(size_t)n * 96 + h * 32 + c] = gate * vn1;
    if (h == 0) v_out[(size_t)n * 96 + 64 + c] = gate * vn2;
}

// ---------------------------------------------------------------- output head
__global__ void out_kernel(const float* __restrict__ s,
                           const float* __restrict__ w1,  // [32][16]
                           const float* __restrict__ w2,  // [16][1]
                           float* __restrict__ out) {
    int n = blockIdx.x * blockDim.x + threadIdx.x;
    if (n >= NNODES) return;
    float sv[NC];
    #pragma unroll
    for (int c = 0; c < NC; ++c) sv[c] = s[(size_t)n * NC + c];
    float e = 0.f;
    #pragma unroll
    for (int j = 0; j < 16; ++j) {
        float tj = 0.f;
        #pragma unroll
        for (int c = 0; c < NC; ++c) tj += sv[c] * w1[c * 16 + j];
        e += tj * w2[j];
    }
    out[n] = e;
}

// ---------------------------------------------------------------- launcher
extern "C" void kernel_launch(void* const* d_in, const int* in_sizes, int n_in,
                              void* d_out, int out_size, void* d_ws, size_t ws_size,
                              hipStream_t stream) {
    const float* vectors   = (const float*)d_in[0];
    const int*   specie    = (const int*)  d_in[1];
    const int*   senders   = (const int*)  d_in[2];
    const int*   receivers = (const int*)  d_in[3];
    const float* emb       = (const float*)d_in[4];
    const float* w_rad1    = (const float*)d_in[5];
    const float* w_rad2    = (const float*)d_in[6];
    const float* w_rad_out = (const float*)d_in[7];
    const float* w_lin_s   = (const float*)d_in[8];
    const float* w_lin_v   = (const float*)d_in[9];
    const float* w_sc_s    = (const float*)d_in[10];
    const float* w_sc_v    = (const float*)d_in[11];
    const float* w_out1    = (const float*)d_in[12];
    const float* w_out2    = (const float*)d_in[13];

    char* base = (char*)d_ws;
    size_t off = 0;
    auto alloc = [&](size_t bytes) { char* q = base + off; off += (bytes + 255) & ~(size_t)255; return q; };

    float* nhat4 = (float*)alloc((size_t)NEDGES * 4 * 4);
    float* rb    = (float*)alloc((size_t)NEDGES * 8 * 4);
    float* s_a   = (float*)alloc((size_t)NNODES * NC * 4);
    float* v_a   = (float*)alloc((size_t)NNODES * NC * 3 * 4);
    float* s_b   = (float*)alloc((size_t)NNODES * NC * 4);
    float* v_b   = (float*)alloc((size_t)NNODES * NC * 3 * 4);
    float* aggs  = (float*)alloc((size_t)NNODES * 2 * NC * 4);
    float* aggv  = (float*)alloc((size_t)NNODES * 3 * NC * 3 * 4);
    int* deg        = (int*)alloc((size_t)NNODES * 4);
    int* rowstart   = (int*)alloc((size_t)(NNODES + 4) * 4);
    int* cursor     = (int*)alloc((size_t)NNODES * 4);
    int* edge_order = (int*)alloc((size_t)NEDGES * 4);
    // big-path extras
    float*    nh_perm  = (float*)alloc((size_t)NEDGES * 4 * 4);
    int*      snd_perm = (int*)alloc((size_t)NEDGES * 4);
    float*    rb_perm  = (float*)alloc((size_t)NEDGES * 8 * 4);
    float*    w1t      = (float*)alloc((size_t)NL * 64 * 8 * 4);
    uint32*   w2p      = (uint32*)alloc((size_t)NL * 32 * 64 * 4);
    uint32*   w3p      = (uint32*)alloc((size_t)NL * 160 * 32 * 4);
    _Float16* wgt16    = (_Float16*)alloc((size_t)NEDGES * 160 * 2);
    bool big = (off <= ws_size);

    geom_kernel<<<(NEDGES + 255) / 256, 256, 0, stream>>>(vectors, nhat4, rb);
    (void)hipMemsetAsync(deg, 0, NNODES * sizeof(int), stream);
    count_kernel<<<(NEDGES + 255) / 256, 256, 0, stream>>>(receivers, deg);
    scan_kernel<<<1, 256, 0, stream>>>(deg, rowstart);
    copy_cursor_kernel<<<(NNODES + 255) / 256, 256, 0, stream>>>(rowstart, cursor);
    fill_kernel<<<(NEDGES + 255) / 256, 256, 0, stream>>>(receivers, cursor, edge_order);
    if (big) {
        perm_kernel<<<(NEDGES + 255) / 256, 256, 0, stream>>>(
            edge_order, senders, nhat4, rb, nh_perm, snd_perm, rb_perm);
        prepw_kernel<<<(NL * (64 * 8 + 32 * 64 + 160 * 32) + 255) / 256, 256, 0, stream>>>(
            w_rad1, w_rad2, w_rad_out, w1t, w2p, w3p);
    }

    init_kernel<<<(NNODES * NC + 255) / 256, 256, 0, stream>>>(specie, emb, s_a);
    (void)hipMemsetAsync(v_a, 0, (size_t)NNODES * NC * 3 * sizeof(float), stream);

    float* si = s_a; float* vi = v_a; float* so = s_b; float* vo = v_b;
    for (int l = 0; l < NL; ++l) {
        if (big) {
            mlpf_kernel<<<(NEDGES + 255) / 256, 256, 0, stream>>>(
                rb_perm,
                w1t + (size_t)l * 64 * 8,
                w2p + (size_t)l * 32 * 64,
                w3p + (size_t)l * 160 * 32,
                wgt16);
            gather_tp_kernel<<<NNODES / 8, 512, 0, stream>>>(
                wgt16, nh_perm, snd_perm, rowstart, deg, si, vi, aggs, aggv);
        } else {
            gather_kernel<<<NNODES / 8, 512, 0, stream>>>(
                rb, nhat4, senders, edge_order, rowstart, deg, si, vi,
                w_rad1 + (size_t)l * NBASIS * NH,
                w_rad2 + (size_t)l * NH * NH,
                w_rad_out + (size_t)l * NH * 160,
                aggs, aggv);
        }
        node_kernel<<<(NNODES + 3) / 4, 256, 0, stream>>>(
            specie, aggs, aggv, si, vi,
            w_lin_s + (size_t)l * 64 * 64,
            w_lin_v + (size_t)l * 96 * 32,
            w_sc_s + (size_t)l * NSPEC * NC * 64,
            w_sc_v + (size_t)l * NSPEC * NC * NC,
            so, vo);
        float* ts = si; si = so; so = ts;
        float* tv = vi; vi = vo; vo = tv;
    }

    out_kernel<<<(NNODES + 255) / 256, 256, 0, stream>>>(si, w_out1, w_out2, (float*)d_out);
}

// Round 11
// 1088.363 us; speedup vs baseline: 4.1663x; 4.1663x over previous
//
#include <hip/hip_runtime.h>
#include <math.h>

#define NNODES 30000
#define NEDGES 480000
#define NC 32
#define NL 3
#define NH 64
#define NBASIS 8
#define NSPEC 5
#define INV_AVG 0.0625f   // 1 / AVG_NEIGH

typedef _Float16 half2v __attribute__((ext_vector_type(2)));
typedef unsigned int uint32;

__device__ __forceinline__ float silu_f(float x) {
    return x / (1.f + __expf(-x));
}
__device__ __forceinline__ float rdlane(float v, int k) {
    return __uint_as_float(__builtin_amdgcn_readlane(__float_as_uint(v), k));
}
__device__ __forceinline__ half2v u2h(uint32 u) {
    union { uint32 u; half2v h; } x; x.u = u; return x.h;
}
__device__ __forceinline__ uint32 packh2(float a, float b) {
    union { uint32 u; half2v h; } x;
    x.h.x = (_Float16)a; x.h.y = (_Float16)b; return x.u;
}

// wgt tile layout: edge gi -> tile T=gi>>6, el=gi&63.
// half h of edge gi lives at  T*10240 + (h>>3)*512 + el*8 + (h&7).

// ---------------------------------------------------------------- geometry
__global__ void geom_kernel(const float* __restrict__ vec,
                            float* __restrict__ nhat4,   // [E][4]
                            float* __restrict__ rb) {    // [E][8]
    int e = blockIdx.x * blockDim.x + threadIdx.x;
    if (e >= NEDGES) return;
    float vx = vec[3*e+0] * 0.25f;   // vectors / R_MAX
    float vy = vec[3*e+1] * 0.25f;
    float vz = vec[3*e+2] * 0.25f;
    float len = sqrtf(vx*vx + vy*vy + vz*vz);      // scaled length
    float inv = 1.f / fmaxf(len, 1e-9f);
    float4 nh = make_float4(vx*inv, vy*inv, vz*inv, 0.f);
    *(float4*)(nhat4 + (size_t)e*4) = nh;
    float x = len * 0.25f;                         // lengths / R_MAX (again)
    float x3 = x*x*x;
    float x6 = x3*x3;
    float x7 = x6*x;
    float x8 = x7*x;
    float env = (x < 1.f) ? (1.f - 28.f*x6 + 48.f*x7 - 21.f*x8) : 0.f;
    float scale = 0.7071067811865476f * inv * env; // sqrt(2/R_MAX)/max(len,eps)*env
    #pragma unroll
    for (int i = 0; i < NBASIS; ++i) {
        rb[NBASIS*e + i] = scale * sinf((float)(i+1) * 3.14159265358979f * x);
    }
}

// ---------------------------------------------------------------- CSR build
__global__ void count_kernel(const int* __restrict__ receivers, int* __restrict__ deg) {
    int e = blockIdx.x * blockDim.x + threadIdx.x;
    if (e >= NEDGES) return;
    atomicAdd(&deg[receivers[e]], 1);
}

__global__ void scan_kernel(const int* __restrict__ deg, int* __restrict__ rowstart) {
    __shared__ int lsum[256];
    __shared__ int loff[256];
    int t = threadIdx.x;
    int lo = t * 118;
    int hi = min(lo + 118, NNODES);
    int s = 0;
    for (int i = lo; i < hi; ++i) s += deg[i];
    lsum[t] = s;
    __syncthreads();
    if (t == 0) {
        int run = 0;
        for (int i = 0; i < 256; ++i) { loff[i] = run; run += lsum[i]; }
    }
    __syncthreads();
    int run = loff[t];
    for (int i = lo; i < hi; ++i) { rowstart[i] = run; run += deg[i]; }
    if (t == 0) rowstart[NNODES] = NEDGES;
}

__global__ void copy_cursor_kernel(const int* __restrict__ rowstart, int* __restrict__ cursor) {
    int i = blockIdx.x * blockDim.x + threadIdx.x;
    if (i < NNODES) cursor[i] = rowstart[i];
}

__global__ void fill_kernel(const int* __restrict__ receivers,
                            int* __restrict__ cursor, int* __restrict__ edge_order) {
    int e = blockIdx.x * blockDim.x + threadIdx.x;
    if (e >= NEDGES) return;
    int pos = atomicAdd(&cursor[receivers[e]], 1);
    edge_order[pos] = e;
}

// ---------------------------------------------------------------- permute edge data (once)
__global__ void perm_kernel(const int* __restrict__ edge_order,
                            const int* __restrict__ senders,
                            const float* __restrict__ nhat4,
                            float* __restrict__ nh_perm, int* __restrict__ snd_perm) {
    int i = blockIdx.x * blockDim.x + threadIdx.x;
    if (i >= NEDGES) return;
    int e = edge_order[i];
    *(float4*)(nh_perm + (size_t)i*4) = *(const float4*)(nhat4 + (size_t)e*4);
    snd_perm[i] = senders[e];
}

// ---------------------------------------------------------------- weight prep (once)
// w1t[l][k][b];  w2p[l][kp][j] = (W2[2kp][j],W2[2kp+1][j]) fp16 pair;
// w3p[l][o][kp] = (W3[2kp][o],W3[2kp+1][o]) fp16 pair
__global__ void prepw_kernel(const float* __restrict__ w1, const float* __restrict__ w2,
                             const float* __restrict__ w3,
                             float* __restrict__ w1t, uint32* __restrict__ w2p,
                             uint32* __restrict__ w3p) {
    int t = blockIdx.x * blockDim.x + threadIdx.x;
    if (t < NL * 64 * 8) {
        int l = t / 512, r = t % 512, k = r >> 3, b = r & 7;
        w1t[t] = w1[l * 512 + b * 64 + k];
    }
    int u = t - NL * 64 * 8;
    if (u >= 0 && u < NL * 32 * 64) {
        int l = u / 2048, r = u % 2048, kp = r >> 6, j = r & 63;
        const float* wl = w2 + l * 4096;
        w2p[u] = packh2(wl[(2*kp) * 64 + j], wl[(2*kp+1) * 64 + j]);
    }
    int v = t - NL * 64 * 8 - NL * 32 * 64;
    if (v >= 0 && v < NL * 160 * 32) {
        int l = v / 5120, r = v % 5120, o = r >> 5, kp = r & 31;
        const float* wl = w3 + l * 10240;
        w3p[v] = packh2(wl[(2*kp) * 160 + o], wl[(2*kp+1) * 160 + o]);
    }
}

// ---------------------------------------------------------------- node init
__global__ void init_kernel(const int* __restrict__ specie,
                            const float* __restrict__ emb,
                            float* __restrict__ s) {
    int t = blockIdx.x * blockDim.x + threadIdx.x;
    if (t >= NNODES * NC) return;
    int n = t >> 5;
    int c = t & 31;
    s[t] = emb[specie[n] * NC + c];
}

// ---------------------------------------------------------------- fused radial MLP
// Thread-per-edge (receiver-sorted order i; rb read via edge_order gather).
// Phase 1: h1 pairs -> dot2 with packed W2 into acc[64] (fp32). Pack acc ->
// h[32] (acc dies -> VGPR drops). Phase 2: 160 outputs via dot2 with packed
// W3; tiled coalesced stores.
__global__ __launch_bounds__(256, 4) void mlpf_kernel(
    const float* __restrict__ rb,          // [E][8] original order
    const int* __restrict__ edge_order,    // [E]
    const float* __restrict__ w1t,         // [64][8]
    const uint32* __restrict__ w2p,        // [32][64]
    const uint32* __restrict__ w3p,        // [160][32]
    _Float16* __restrict__ wgt16)          // tiled layout
{
    int i = blockIdx.x * 256 + threadIdx.x;
    if (i >= NEDGES) return;
    int e = edge_order[i];
    float4 ra = *(const float4*)(rb + (size_t)e * 8);
    float4 rv = *(const float4*)(rb + (size_t)e * 8 + 4);

    float acc[NH];
    #pragma unroll
    for (int j = 0; j < NH; ++j) acc[j] = 0.f;

    #pragma unroll 1
    for (int kp = 0; kp < 32; ++kp) {
        const float* wk = w1t + kp * 16;
        float h0, h1v;
        h0 = ra.x * wk[0];
        h0 = fmaf(ra.y, wk[1], h0);
        h0 = fmaf(ra.z, wk[2], h0);
        h0 = fmaf(ra.w, wk[3], h0);
        h0 = fmaf(rv.x, wk[4], h0);
        h0 = fmaf(rv.y, wk[5], h0);
        h0 = fmaf(rv.z, wk[6], h0);
        h0 = fmaf(rv.w, wk[7], h0);
        h1v = ra.x * wk[8];
        h1v = fmaf(ra.y, wk[9],  h1v);
        h1v = fmaf(ra.z, wk[10], h1v);
        h1v = fmaf(ra.w, wk[11], h1v);
        h1v = fmaf(rv.x, wk[12], h1v);
        h1v = fmaf(rv.y, wk[13], h1v);
        h1v = fmaf(rv.z, wk[14], h1v);
        h1v = fmaf(rv.w, wk[15], h1v);
        uint32 hp = packh2(silu_f(h0), silu_f(h1v));
        const uint32* w2k = w2p + kp * 64;
        #pragma unroll
        for (int j = 0; j < NH; ++j)
            acc[j] = __builtin_amdgcn_fdot2(u2h(hp), u2h(w2k[j]), acc[j], false);
    }

    // pack h2 -> 32 uints; acc dies here (register pressure drops)
    uint32 h[32];
    #pragma unroll
    for (int q = 0; q < 32; ++q)
        h[q] = packh2(silu_f(acc[2*q]), silu_f(acc[2*q+1]));

    _Float16* tp = wgt16 + (size_t)(i >> 6) * 10240 + (i & 63) * 8;
    #pragma unroll 1
    for (int ob = 0; ob < 160; ob += 8) {
        float t[8];
        #pragma unroll
        for (int o = 0; o < 8; ++o) {
            const uint32* wr = w3p + (ob + o) * 32;
            float a = 0.f;
            #pragma unroll
            for (int kp = 0; kp < 32; ++kp)
                a = __builtin_amdgcn_fdot2(u2h(h[kp]), u2h(wr[kp]), a, false);
            t[o] = a;
        }
        uint4 pk;
        pk.x = packh2(t[0], t[1]);
        pk.y = packh2(t[2], t[3]);
        pk.z = packh2(t[4], t[5]);
        pk.w = packh2(t[6], t[7]);
        *(uint4*)(tp + (ob >> 3) * 512) = pk;
    }
}

// ---------------------------------------------------------------- gather + TP
// Wave per node; prefetch next edge's snd/nh to break the load->use chain.
__global__ __launch_bounds__(512) void gather_tp_kernel(
    const _Float16* __restrict__ wgt16,   // tiled layout
    const float* __restrict__ nh_perm,    // [E][4]
    const int* __restrict__ snd_perm,     // [E]
    const int* __restrict__ rowstart, const int* __restrict__ deg,
    const float* __restrict__ s_in, const float* __restrict__ v_in,  // v: [N][3][32]
    float* __restrict__ agg_s,      // [N][64]
    float* __restrict__ agg_v)      // [N][96][3]
{
    int lane = threadIdx.x & 63;
    int wid  = threadIdx.x >> 6;
    int n = blockIdx.x * 8 + wid;
    if (n >= NNODES) return;

    int c = lane & 31;
    int half = lane >> 5;
    int off01 = half * 32 + c;

    int o0 = ((off01 >> 3) << 9) + (off01 & 7);            // half index off01
    int o2 = (((128 + c) >> 3) << 9) + (c & 7);            // half index 128+c

    float accS = 0.f;
    float aVa0 = 0.f, aVa1 = 0.f, aVa2 = 0.f;   // half0: path2, half1: path3
    float aVb0 = 0.f, aVb1 = 0.f, aVb2 = 0.f;   // half0: path4, half1: garbage

    int start = rowstart[n];
    int cnt   = deg[n];

    int snd_n = 0;
    float4 nh_n = make_float4(0.f, 0.f, 0.f, 0.f);
    if (cnt > 0) {
        snd_n = snd_perm[start];
        nh_n  = *(const float4*)(nh_perm + (size_t)start * 4);
    }

    for (int i = 0; i < cnt; ++i) {
        int idx = start + i;
        int snd = snd_n;
        float4 nh = nh_n;
        const _Float16* tp = wgt16 + (size_t)(idx >> 6) * 10240 + (idx & 63) * 8;

        float d0  = (float)tp[o0];           // half0: wgt0[c]  half1: wgt1[c]
        float d1  = (float)tp[o0 + 4096];    // half0: wgt2[c]  half1: wgt3[c]
        float d2f = (float)tp[o2];           // wgt4[c] (half1 discards)

        // prefetch next edge's snd/nh (independent of this iteration's chain)
        if (i + 1 < cnt) {
            snd_n = snd_perm[idx + 1];
            nh_n  = *(const float4*)(nh_perm + (size_t)(idx + 1) * 4);
        }

        float su = s_in[(size_t)snd * NC + c];
        float v0 = v_in[(size_t)snd * 96 + c];
        float v1 = v_in[(size_t)snd * 96 + 32 + c];
        float v2 = v_in[(size_t)snd * 96 + 64 + c];
        float ndv = nh.x * v0;
        ndv = fmaf(nh.y, v1, ndv);
        ndv = fmaf(nh.z, v2, ndv);

        float sSel = half ? ndv : su;          // path1 vs path0 multiplier
        accS = fmaf(d0, sSel, accS);
        float scale = half ? d1 : d1 * su;     // path3: w3 ; path2: w2*su
        float f0 = half ? v0 : nh.x;
        float f1 = half ? v1 : nh.y;
        float f2 = half ? v2 : nh.z;
        aVa0 = fmaf(scale, f0, aVa0);
        aVa1 = fmaf(scale, f1, aVa1);
        aVa2 = fmaf(scale, f2, aVa2);
        float m4 = half ? 0.f : d2f;           // path4 only on half0
        aVb0 = fmaf(m4, fmaf(nh.x, ndv, -v0 * (1.f / 3.f)), aVb0);
        aVb1 = fmaf(m4, fmaf(nh.y, ndv, -v1 * (1.f / 3.f)), aVb1);
        aVb2 = fmaf(m4, fmaf(nh.z, ndv, -v2 * (1.f / 3.f)), aVb2);
    }

    agg_s[(size_t)n * 64 + lane] = accS;
    float* av = agg_v + (size_t)n * 288;
    if (half == 0) {
        av[c * 3 + 0] = aVa0; av[c * 3 + 1] = aVa1; av[c * 3 + 2] = aVa2;                      // path2
        av[(64 + c) * 3 + 0] = aVb0; av[(64 + c) * 3 + 1] = aVb1; av[(64 + c) * 3 + 2] = aVb2; // path4
    } else {
        av[(32 + c) * 3 + 0] = aVa0; av[(32 + c) * 3 + 1] = aVa1; av[(32 + c) * 3 + 2] = aVa2; // path3
    }
}

// ---------------------------------------------------------------- fallback gather (Round-2)
__global__ __launch_bounds__(512) void gather_kernel(
    const float* __restrict__ rb, const float* __restrict__ nhat4,
    const int* __restrict__ senders, const int* __restrict__ edge_order,
    const int* __restrict__ rowstart, const int* __restrict__ deg,
    const float* __restrict__ s_in, const float* __restrict__ v_in,
    const float* __restrict__ w1, const float* __restrict__ w2, const float* __restrict__ w3,
    float* __restrict__ agg_s, float* __restrict__ agg_v)
{
    __shared__ float sW2[NH * NH];
    __shared__ float sW3[NH * 160];
    for (int i = threadIdx.x; i < NH * NH;  i += 512) sW2[i] = w2[i];
    for (int i = threadIdx.x; i < NH * 160; i += 512) sW3[i] = w3[i];
    __syncthreads();
    int lane = threadIdx.x & 63;
    int wid  = threadIdx.x >> 6;
    int n = blockIdx.x * 8 + wid;
    if (n >= NNODES) return;
    int c = lane & 31;
    int half = lane >> 5;
    float w1r[8];
    #pragma unroll
    for (int b = 0; b < 8; ++b) w1r[b] = w1[b * NH + lane];
    float accS = 0.f;
    float aVa0 = 0.f, aVa1 = 0.f, aVa2 = 0.f;
    float aVb0 = 0.f, aVb1 = 0.f, aVb2 = 0.f;
    int start = rowstart[n];
    int cnt   = deg[n];
    for (int i = 0; i < cnt; ++i) {
        int e   = edge_order[start + i];
        int snd = senders[e];
        float4 nh  = *(const float4*)(nhat4 + (size_t)e * 4);
        float4 rba = *(const float4*)(rb + (size_t)e * 8);
        float4 rbb = *(const float4*)(rb + (size_t)e * 8 + 4);
        float h1v;
        h1v = rba.x * w1r[0];
        h1v = fmaf(rba.y, w1r[1], h1v);
        h1v = fmaf(rba.z, w1r[2], h1v);
        h1v = fmaf(rba.w, w1r[3], h1v);
        h1v = fmaf(rbb.x, w1r[4], h1v);
        h1v = fmaf(rbb.y, w1r[5], h1v);
        h1v = fmaf(rbb.z, w1r[6], h1v);
        h1v = fmaf(rbb.w, w1r[7], h1v);
        h1v = silu_f(h1v);
        float a0 = 0.f, a1 = 0.f;
        #pragma unroll
        for (int k = 0; k < NH; k += 2) {
            a0 = fmaf(rdlane(h1v, k),     sW2[k * NH + lane],       a0);
            a1 = fmaf(rdlane(h1v, k + 1), sW2[(k + 1) * NH + lane], a1);
        }
        float h2v = silu_f(a0 + a1);
        float d0a = 0.f, d0b = 0.f, d1a = 0.f, d1b = 0.f, d2a = 0.f, d2b = 0.f;
        #pragma unroll
        for (int k = 0; k < NH; k += 2) {
            float hA = rdlane(h2v, k);
            float hB = rdlane(h2v, k + 1);
            d0a = fmaf(hA, sW3[k * 160 + lane],            d0a);
            d1a = fmaf(hA, sW3[k * 160 + 64 + lane],       d1a);
            d2a = fmaf(hA, sW3[k * 160 + 128 + c],         d2a);
            d0b = fmaf(hB, sW3[(k + 1) * 160 + lane],      d0b);
            d1b = fmaf(hB, sW3[(k + 1) * 160 + 64 + lane], d1b);
            d2b = fmaf(hB, sW3[(k + 1) * 160 + 128 + c],   d2b);
        }
        float d0 = d0a + d0b;
        float d1 = d1a + d1b;
        float d2 = d2a + d2b;
        float su = s_in[(size_t)snd * NC + c];
        float v0 = v_in[(size_t)snd * 96 + c];
        float v1 = v_in[(size_t)snd * 96 + 32 + c];
        float v2 = v_in[(size_t)snd * 96 + 64 + c];
        float ndv = nh.x * v0;
        ndv = fmaf(nh.y, v1, ndv);
        ndv = fmaf(nh.z, v2, ndv);
        float sSel = half ? ndv : su;
        accS = fmaf(d0, sSel, accS);
        float scale = half ? d1 : d1 * su;
        float f0 = half ? v0 : nh.x;
        float f1 = half ? v1 : nh.y;
        float f2 = half ? v2 : nh.z;
        aVa0 = fmaf(scale, f0, aVa0);
        aVa1 = fmaf(scale, f1, aVa1);
        aVa2 = fmaf(scale, f2, aVa2);
        float m4 = half ? 0.f : d2;
        aVb0 = fmaf(m4, fmaf(nh.x, ndv, -v0 * (1.f / 3.f)), aVb0);
        aVb1 = fmaf(m4, fmaf(nh.y, ndv, -v1 * (1.f / 3.f)), aVb1);
        aVb2 = fmaf(m4, fmaf(nh.z, ndv, -v2 * (1.f / 3.f)), aVb2);
    }
    agg_s[(size_t)n * 64 + lane] = accS;
    float* av = agg_v + (size_t)n * 288;
    if (half == 0) {
        av[c * 3 + 0] = aVa0; av[c * 3 + 1] = aVa1; av[c * 3 + 2] = aVa2;
        av[(64 + c) * 3 + 0] = aVb0; av[(64 + c) * 3 + 1] = aVb1; av[(64 + c) * 3 + 2] = aVb2;
    } else {
        av[(32 + c) * 3 + 0] = aVa0; av[(32 + c) * 3 + 1] = aVa1; av[(32 + c) * 3 + 2] = aVa2;
    }
}

// ---------------------------------------------------------------- node update (v2)
__global__ __launch_bounds__(256) void node_kernel(
    const int* __restrict__ specie,
    const float* __restrict__ agg_s, const float* __restrict__ agg_v,
    const float* __restrict__ s_in,  const float* __restrict__ v_in,
    const float* __restrict__ wls,   // [64][64]
    const float* __restrict__ wlv,   // [96][32]
    const float* __restrict__ wscs,  // [5][32][64]
    const float* __restrict__ wscv,  // [5][32][32]
    float* __restrict__ s_out, float* __restrict__ v_out)
{
    __shared__ float sAV[4][288];
    __shared__ float sVO[4][96];

    int lane = threadIdx.x & 63;
    int wid  = threadIdx.x >> 6;
    int n = blockIdx.x * 4 + wid;
    if (n >= NNODES) return;
    int sp = specie[n];

    const float* av = agg_v + (size_t)n * 288;
    sAV[wid][lane]       = av[lane];
    sAV[wid][64 + lane]  = av[64 + lane];
    sAV[wid][128 + lane] = av[128 + lane];
    sAV[wid][192 + lane] = av[192 + lane];
    if (lane < 32) sAV[wid][256 + lane] = av[256 + lane];
    const float* vo = v_in + (size_t)n * 96;
    if (lane < 32) {
        sVO[wid][lane]      = vo[lane];
        sVO[wid][32 + lane] = vo[32 + lane];
        sVO[wid][64 + lane] = vo[64 + lane];
    }

    float asv = agg_s[(size_t)n * 64 + lane];
    float sv  = s_in[(size_t)n * 32 + (lane & 31)];

    __syncthreads();

    float sg = 0.f;
    #pragma unroll
    for (int j = 0; j < 64; ++j)
        sg = fmaf(rdlane(asv, j), wls[j * 64 + lane], sg);
    sg *= INV_AVG;
    const float* ws = wscs + (size_t)sp * 32 * 64;
    #pragma unroll
    for (int j = 0; j < 32; ++j)
        sg = fmaf(rdlane(sv, j), ws[j * 64 + lane], sg);
    float act  = silu_f(sg);
    float gate = __shfl(act, (lane & 31) + 32);

    int c = lane & 31;
    int h = lane >> 5;
    float vn1 = 0.f, vn2 = 0.f;
    #pragma unroll
    for (int p = 0; p < 96; ++p) {
        float w = wlv[p * 32 + c];
        vn1 = fmaf(sAV[wid][3 * p + h], w, vn1);
        vn2 = fmaf(sAV[wid][3 * p + 2], w, vn2);
    }
    vn1 *= INV_AVG; vn2 *= INV_AVG;
    const float* wv = wscv + (size_t)sp * 32 * 32;
    #pragma unroll
    for (int j = 0; j < 32; ++j) {
        float w = wv[j * 32 + c];
        vn1 = fmaf(sVO[wid][h * 32 + j], w, vn1);
        vn2 = fmaf(sVO[wid][64 + j],     w, vn2);
    }

    if (lane < 32) s_out[(size_t)n * 32 + lane] = act;
    v_out[(size_t)n * 96 + h * 32 + c] = gate * vn1;
    if (h == 0) v_out[(size_t)n * 96 + 64 + c] = gate * vn2;
}

// ---------------------------------------------------------------- output head
__global__ void out_kernel(const float* __restrict__ s,
                           const float* __restrict__ w1,  // [32][16]
                           const float* __restrict__ w2,  // [16][1]
                           float* __restrict__ out) {
    int n = blockIdx.x * blockDim.x + threadIdx.x;
    if (n >= NNODES) return;
    float sv[NC];
    #pragma unroll
    for (int c = 0; c < NC; ++c) sv[c] = s[(size_t)n * NC + c];
    float e = 0.f;
    #pragma unroll
    for (int j = 0; j < 16; ++j) {
        float tj = 0.f;
        #pragma unroll
        for (int c = 0; c < NC; ++c) tj += sv[c] * w1[c * 16 + j];
        e += tj * w2[j];
    }
    out[n] = e;
}

// ---------------------------------------------------------------- launcher
extern "C" void kernel_launch(void* const* d_in, const int* in_sizes, int n_in,
                              void* d_out, int out_size, void* d_ws, size_t ws_size,
                              hipStream_t stream) {
    const float* vectors   = (const float*)d_in[0];
    const int*   specie    = (const int*)  d_in[1];
    const int*   senders   = (const int*)  d_in[2];
    const int*   receivers = (const int*)  d_in[3];
    const float* emb       = (const float*)d_in[4];
    const float* w_rad1    = (const float*)d_in[5];
    const float* w_rad2    = (const float*)d_in[6];
    const float* w_rad_out = (const float*)d_in[7];
    const float* w_lin_s   = (const float*)d_in[8];
    const float* w_lin_v   = (const float*)d_in[9];
    const float* w_sc_s    = (const float*)d_in[10];
    const float* w_sc_v    = (const float*)d_in[11];
    const float* w_out1    = (const float*)d_in[12];
    const float* w_out2    = (const float*)d_in[13];

    char* base = (char*)d_ws;
    size_t off = 0;
    auto alloc = [&](size_t bytes) { char* q = base + off; off += (bytes + 255) & ~(size_t)255; return q; };

    float* nhat4 = (float*)alloc((size_t)NEDGES * 4 * 4);
    float* rb    = (float*)alloc((size_t)NEDGES * 8 * 4);
    float* s_a   = (float*)alloc((size_t)NNODES * NC * 4);
    float* v_a   = (float*)alloc((size_t)NNODES * NC * 3 * 4);
    float* s_b   = (float*)alloc((size_t)NNODES * NC * 4);
    float* v_b   = (float*)alloc((size_t)NNODES * NC * 3 * 4);
    float* aggs  = (float*)alloc((size_t)NNODES * 2 * NC * 4);
    float* aggv  = (float*)alloc((size_t)NNODES * 3 * NC * 3 * 4);
    int* deg        = (int*)alloc((size_t)NNODES * 4);
    int* rowstart   = (int*)alloc((size_t)(NNODES + 4) * 4);
    int* cursor     = (int*)alloc((size_t)NNODES * 4);
    int* edge_order = (int*)alloc((size_t)NEDGES * 4);
    // big-path extras
    float*    nh_perm  = (float*)alloc((size_t)NEDGES * 4 * 4);
    int*      snd_perm = (int*)alloc((size_t)NEDGES * 4);
    float*    w1t      = (float*)alloc((size_t)NL * 64 * 8 * 4);
    uint32*   w2p      = (uint32*)alloc((size_t)NL * 32 * 64 * 4);
    uint32*   w3p      = (uint32*)alloc((size_t)NL * 160 * 32 * 4);
    _Float16* wgt16    = (_Float16*)alloc((size_t)NEDGES * 160 * 2);
    bool big = (off <= ws_size);

    geom_kernel<<<(NEDGES + 255) / 256, 256, 0, stream>>>(vectors, nhat4, rb);
    (void)hipMemsetAsync(deg, 0, NNODES * sizeof(int), stream);
    count_kernel<<<(NEDGES + 255) / 256, 256, 0, stream>>>(receivers, deg);
    scan_kernel<<<1, 256, 0, stream>>>(deg, rowstart);
    copy_cursor_kernel<<<(NNODES + 255) / 256, 256, 0, stream>>>(rowstart, cursor);
    fill_kernel<<<(NEDGES + 255) / 256, 256, 0, stream>>>(receivers, cursor, edge_order);
    if (big) {
        perm_kernel<<<(NEDGES + 255) / 256, 256, 0, stream>>>(
            edge_order, senders, nhat4, nh_perm, snd_perm);
        prepw_kernel<<<(NL * (64 * 8 + 32 * 64 + 160 * 32) + 255) / 256, 256, 0, stream>>>(
            w_rad1, w_rad2, w_rad_out, w1t, w2p, w3p);
    }

    init_kernel<<<(NNODES * NC + 255) / 256, 256, 0, stream>>>(specie, emb, s_a);
    (void)hipMemsetAsync(v_a, 0, (size_t)NNODES * NC * 3 * sizeof(float), stream);

    float* si = s_a; float* vi = v_a; float* so = s_b; float* vo = v_b;
    for (int l = 0; l < NL; ++l) {
        if (big) {
            mlpf_kernel<<<(NEDGES + 255) / 256, 256, 0, stream>>>(
                rb, edge_order,
                w1t + (size_t)l * 64 * 8,
                w2p + (size_t)l * 32 * 64,
                w3p + (size_t)l * 160 * 32,
                wgt16);
            gather_tp_kernel<<<NNODES / 8, 512, 0, stream>>>(
                wgt16, nh_perm, snd_perm, rowstart, deg, si, vi, aggs, aggv);
        } else {
            gather_kernel<<<NNODES / 8, 512, 0, stream>>>(
                rb, nhat4, senders, edge_order, rowstart, deg, si, vi,
                w_rad1 + (size_t)l * NBASIS * NH,
                w_rad2 + (size_t)l * NH * NH,
                w_rad_out + (size_t)l * NH * 160,
                aggs, aggv);
        }
        node_kernel<<<(NNODES + 3) / 4, 256, 0, stream>>>(
            specie, aggs, aggv, si, vi,
            w_lin_s + (size_t)l * 64 * 64,
            w_lin_v + (size_t)l * 96 * 32,
            w_sc_s + (size_t)l * NSPEC * NC * 64,
            w_sc_v + (size_t)l * NSPEC * NC * NC,
            so, vo);
        float* ts = si; si = so; so = ts;
        float* tv = vi; vi = vo; vo = tv;
    }

    out_kernel<<<(NNODES + 255) / 256, 256, 0, stream>>>(si, w_out1, w_out2, (float*)d_out);
}

// Round 12
// 744.150 us; speedup vs baseline: 6.0935x; 1.4626x over previous
//
#include <hip/hip_runtime.h>
#include <math.h>

#define NNODES 30000
#define NEDGES 480000
#define NC 32
#define NL 3
#define NH 64
#define NBASIS 8
#define NSPEC 5
#define INV_AVG 0.0625f   // 1 / AVG_NEIGH

typedef _Float16 half2v __attribute__((ext_vector_type(2)));
typedef _Float16 half4v __attribute__((ext_vector_type(4)));
typedef _Float16 half8v __attribute__((ext_vector_type(8)));
typedef float    float4v __attribute__((ext_vector_type(4)));
typedef unsigned int uint32;

__device__ __forceinline__ float silu_f(float x) {
    return x / (1.f + __expf(-x));
}
__device__ __forceinline__ float rdlane(float v, int k) {
    return __uint_as_float(__builtin_amdgcn_readlane(__float_as_uint(v), k));
}

// wgt16 layout (matches W3 MFMA C-fragments):
//   edge gi, output h (0..159):  g=gi>>4, rg=(gi&15)>>2, reg=gi&3, nt=h>>4, c16=h&15
//   f16 index = g*2560 + nt*256 + rg*64 + c16*4 + reg

// ---------------------------------------------------------------- geometry
__global__ void geom_kernel(const float* __restrict__ vec,
                            float* __restrict__ nhat4,   // [E][4]
                            float* __restrict__ rb) {    // [E][8]
    int e = blockIdx.x * blockDim.x + threadIdx.x;
    if (e >= NEDGES) return;
    float vx = vec[3*e+0] * 0.25f;   // vectors / R_MAX
    float vy = vec[3*e+1] * 0.25f;
    float vz = vec[3*e+2] * 0.25f;
    float len = sqrtf(vx*vx + vy*vy + vz*vz);      // scaled length
    float inv = 1.f / fmaxf(len, 1e-9f);
    float4 nh = make_float4(vx*inv, vy*inv, vz*inv, 0.f);
    *(float4*)(nhat4 + (size_t)e*4) = nh;
    float x = len * 0.25f;                         // lengths / R_MAX (again)
    float x3 = x*x*x;
    float x6 = x3*x3;
    float x7 = x6*x;
    float x8 = x7*x;
    float env = (x < 1.f) ? (1.f - 28.f*x6 + 48.f*x7 - 21.f*x8) : 0.f;
    float scale = 0.7071067811865476f * inv * env; // sqrt(2/R_MAX)/max(len,eps)*env
    #pragma unroll
    for (int i = 0; i < NBASIS; ++i) {
        rb[NBASIS*e + i] = scale * sinf((float)(i+1) * 3.14159265358979f * x);
    }
}

// ---------------------------------------------------------------- CSR build
__global__ void count_kernel(const int* __restrict__ receivers, int* __restrict__ deg) {
    int e = blockIdx.x * blockDim.x + threadIdx.x;
    if (e >= NEDGES) return;
    atomicAdd(&deg[receivers[e]], 1);
}

__global__ void scan_kernel(const int* __restrict__ deg, int* __restrict__ rowstart) {
    __shared__ int lsum[256];
    __shared__ int loff[256];
    int t = threadIdx.x;
    int lo = t * 118;
    int hi = min(lo + 118, NNODES);
    int s = 0;
    for (int i = lo; i < hi; ++i) s += deg[i];
    lsum[t] = s;
    __syncthreads();
    if (t == 0) {
        int run = 0;
        for (int i = 0; i < 256; ++i) { loff[i] = run; run += lsum[i]; }
    }
    __syncthreads();
    int run = loff[t];
    for (int i = lo; i < hi; ++i) { rowstart[i] = run; run += deg[i]; }
    if (t == 0) rowstart[NNODES] = NEDGES;
}

__global__ void copy_cursor_kernel(const int* __restrict__ rowstart, int* __restrict__ cursor) {
    int i = blockIdx.x * blockDim.x + threadIdx.x;
    if (i < NNODES) cursor[i] = rowstart[i];
}

__global__ void fill_kernel(const int* __restrict__ receivers,
                            int* __restrict__ cursor, int* __restrict__ edge_order) {
    int e = blockIdx.x * blockDim.x + threadIdx.x;
    if (e >= NEDGES) return;
    int pos = atomicAdd(&cursor[receivers[e]], 1);
    edge_order[pos] = e;
}

// ---------------------------------------------------------------- permute edge data (once)
__global__ void perm_kernel(const int* __restrict__ edge_order,
                            const int* __restrict__ senders,
                            const float* __restrict__ nhat4,
                            float* __restrict__ nh_perm, int* __restrict__ snd_perm) {
    int i = blockIdx.x * blockDim.x + threadIdx.x;
    if (i >= NEDGES) return;
    int e = edge_order[i];
    *(float4*)(nh_perm + (size_t)i*4) = *(const float4*)(nhat4 + (size_t)e*4);
    snd_perm[i] = senders[e];
}

// ---------------------------------------------------------------- weight prep (once)
// w1t[l][k][b] f32 (transposed W1)
// w2f[l][ks][nt][lane][e] f16: W2[ks*32 + (lane>>4)*8 + e][nt*16 + (lane&15)]
// w3f[l][ks][nt][lane][e] f16: W3[ks*32 + (lane>>4)*8 + e][nt*16 + (lane&15)]
__global__ void prepw_kernel(const float* __restrict__ w1, const float* __restrict__ w2,
                             const float* __restrict__ w3,
                             float* __restrict__ w1t, _Float16* __restrict__ w2f,
                             _Float16* __restrict__ w3f) {
    int t = blockIdx.x * blockDim.x + threadIdx.x;
    if (t < NL * 64 * 8) {
        int l = t / 512, r = t % 512, k = r >> 3, b = r & 7;
        w1t[t] = w1[l * 512 + b * 64 + k];
    }
    int u = t - NL * 64 * 8;
    if (u >= 0 && u < NL * 2 * 4 * 64 * 8) {
        int e = u & 7, lane = (u >> 3) & 63, nt = (u >> 9) & 3, ks = (u >> 11) & 1, l = u >> 12;
        int k = ks * 32 + ((lane >> 4) << 3) + e;
        int col = nt * 16 + (lane & 15);
        w2f[u] = (_Float16)w2[l * 4096 + k * 64 + col];
    }
    int v = t - NL * 64 * 8 - NL * 2 * 4 * 64 * 8;
    if (v >= 0 && v < NL * 2 * 10 * 64 * 8) {
        int q = v / 5120, rem = v % 5120;
        int l = q >> 1, ks = q & 1;
        int nt = rem >> 9, lane = (rem >> 3) & 63, e = rem & 7;
        int k = ks * 32 + ((lane >> 4) << 3) + e;
        int col = nt * 16 + (lane & 15);
        w3f[v] = (_Float16)w3[l * 10240 + k * 160 + col];
    }
}

// ---------------------------------------------------------------- node init
__global__ void init_kernel(const int* __restrict__ specie,
                            const float* __restrict__ emb,
                            float* __restrict__ s) {
    int t = blockIdx.x * blockDim.x + threadIdx.x;
    if (t >= NNODES * NC) return;
    int n = t >> 5;
    int c = t & 31;
    s[t] = emb[specie[n] * NC + c];
}

// ---------------------------------------------------------------- MFMA radial MLP
// One wave per 16 edges (block = 4 waves = 64 edges). Lane (c16=l&15, kg=l>>4):
//  h1: lane computes h1[edge=c16][k=kg*8+e] and [32+kg*8+e] directly (VALU,
//      W1 from LDS) -> exactly the two A-fragments for the W2 MFMAs.
//  h2: 8x mfma_16x16x32_f16 with fragment-order W2 table; silu -> padded LDS
//      tile -> re-read as A-frags.
//  wgt: 20x MFMA with W3 table; C-fragments stored directly (coalesced 8B/lane).
__global__ __launch_bounds__(256) void mlpm_kernel(
    const float* __restrict__ rb,          // [E][8] original order
    const int* __restrict__ edge_order,    // [E]
    const float* __restrict__ w1t,         // [64][8] f32
    const _Float16* __restrict__ w2f,      // [2][4][64][8]
    const _Float16* __restrict__ w3f,      // [2][10][64][8]
    _Float16* __restrict__ wgt16)          // fragment layout
{
    __shared__ float w1lds[512];
    __shared__ _Float16 tile[4][16][72];   // h2 tile, padded stride 72

    for (int t = threadIdx.x; t < 512; t += 256) w1lds[t] = w1t[t];
    __syncthreads();

    int lane = threadIdx.x & 63;
    int wid  = threadIdx.x >> 6;
    int c16 = lane & 15;
    int kg  = lane >> 4;
    int ibase = blockIdx.x * 64 + wid * 16;
    int g = blockIdx.x * 4 + wid;

    // ---- h1 (VALU): 16 values per lane, directly in A-frag layout
    int e_orig = edge_order[ibase + c16];
    float4 ra4 = *(const float4*)(rb + (size_t)e_orig * 8);
    float4 rb4 = *(const float4*)(rb + (size_t)e_orig * 8 + 4);

    half8v a0, a1;
    #pragma unroll
    for (int e = 0; e < 8; ++e) {
        const float* wr0 = w1lds + (kg * 8 + e) * 8;
        float d0;
        d0 = ra4.x * wr0[0];
        d0 = fmaf(ra4.y, wr0[1], d0);
        d0 = fmaf(ra4.z, wr0[2], d0);
        d0 = fmaf(ra4.w, wr0[3], d0);
        d0 = fmaf(rb4.x, wr0[4], d0);
        d0 = fmaf(rb4.y, wr0[5], d0);
        d0 = fmaf(rb4.z, wr0[6], d0);
        d0 = fmaf(rb4.w, wr0[7], d0);
        a0[e] = (_Float16)silu_f(d0);
        const float* wr1 = w1lds + (32 + kg * 8 + e) * 8;
        float d1;
        d1 = ra4.x * wr1[0];
        d1 = fmaf(ra4.y, wr1[1], d1);
        d1 = fmaf(ra4.z, wr1[2], d1);
        d1 = fmaf(ra4.w, wr1[3], d1);
        d1 = fmaf(rb4.x, wr1[4], d1);
        d1 = fmaf(rb4.y, wr1[5], d1);
        d1 = fmaf(rb4.z, wr1[6], d1);
        d1 = fmaf(rb4.w, wr1[7], d1);
        a1[e] = (_Float16)silu_f(d1);
    }

    // ---- h2 via W2 MFMA (M=16 edges, N=64, K=64)
    _Float16* tw = &tile[wid][0][0];
    float4v zero4 = {0.f, 0.f, 0.f, 0.f};
    #pragma unroll
    for (int nt = 0; nt < 4; ++nt) {
        half8v b0 = *(const half8v*)(w2f + (size_t)(nt) * 512 + lane * 8);
        half8v b1 = *(const half8v*)(w2f + (size_t)(4 + nt) * 512 + lane * 8);
        float4v acc = __builtin_amdgcn_mfma_f32_16x16x32_f16(a0, b0, zero4, 0, 0, 0);
        acc = __builtin_amdgcn_mfma_f32_16x16x32_f16(a1, b1, acc, 0, 0, 0);
        #pragma unroll
        for (int r = 0; r < 4; ++r)
            tw[(kg * 4 + r) * 72 + nt * 16 + c16] = (_Float16)silu_f(acc[r]);
    }

    // re-read h2 as A-frags (row = c16, k = ks*32 + kg*8 + e)
    half8v a2 = *(const half8v*)(tw + c16 * 72 + kg * 8);
    half8v a3 = *(const half8v*)(tw + c16 * 72 + 32 + kg * 8);

    // ---- wgt via W3 MFMA (N=160), store C-fragments directly
    _Float16* out = wgt16 + (size_t)g * 2560 + lane * 4;
    #pragma unroll
    for (int nt = 0; nt < 10; ++nt) {
        half8v b0 = *(const half8v*)(w3f + (size_t)(nt) * 512 + lane * 8);
        half8v b1 = *(const half8v*)(w3f + (size_t)(10 + nt) * 512 + lane * 8);
        float4v acc = __builtin_amdgcn_mfma_f32_16x16x32_f16(a2, b0, zero4, 0, 0, 0);
        acc = __builtin_amdgcn_mfma_f32_16x16x32_f16(a3, b1, acc, 0, 0, 0);
        half4v o;
        o[0] = (_Float16)acc[0];
        o[1] = (_Float16)acc[1];
        o[2] = (_Float16)acc[2];
        o[3] = (_Float16)acc[3];
        *(half4v*)(out + nt * 256) = o;
    }
}

// ---------------------------------------------------------------- gather + TP
// Wave per node; prefetch next edge's snd/nh to break the load->use chain.
__global__ __launch_bounds__(512) void gather_tp_kernel(
    const _Float16* __restrict__ wgt16,   // fragment layout
    const float* __restrict__ nh_perm,    // [E][4]
    const int* __restrict__ snd_perm,     // [E]
    const int* __restrict__ rowstart, const int* __restrict__ deg,
    const float* __restrict__ s_in, const float* __restrict__ v_in,  // v: [N][3][32]
    float* __restrict__ agg_s,      // [N][64]
    float* __restrict__ agg_v)      // [N][96][3]
{
    int lane = threadIdx.x & 63;
    int wid  = threadIdx.x >> 6;
    int n = blockIdx.x * 8 + wid;
    if (n >= NNODES) return;

    int c = lane & 31;
    int half = lane >> 5;

    // per-lane constant offsets into a 2560-f16 edge-group block
    int c16g = c & 15;
    int off0 = (2 * half + (c >> 4)) * 256 + c16g * 4;        // h = half*32+c
    int off1 = (4 + 2 * half + (c >> 4)) * 256 + c16g * 4;    // h = 64+half*32+c
    int off2 = (8 + (c >> 4)) * 256 + c16g * 4;               // h = 128+c

    float accS = 0.f;
    float aVa0 = 0.f, aVa1 = 0.f, aVa2 = 0.f;   // half0: path2, half1: path3
    float aVb0 = 0.f, aVb1 = 0.f, aVb2 = 0.f;   // half0: path4, half1: garbage

    int start = rowstart[n];
    int cnt   = deg[n];

    int snd_n = 0;
    float4 nh_n = make_float4(0.f, 0.f, 0.f, 0.f);
    if (cnt > 0) {
        snd_n = snd_perm[start];
        nh_n  = *(const float4*)(nh_perm + (size_t)start * 4);
    }

    for (int i = 0; i < cnt; ++i) {
        int idx = start + i;
        int snd = snd_n;
        float4 nh = nh_n;
        size_t base_e = (size_t)(idx >> 4) * 2560 + ((idx & 15) >> 2) * 64 + (idx & 3);

        float d0  = (float)wgt16[base_e + off0];
        float d1  = (float)wgt16[base_e + off1];
        float d2f = (float)wgt16[base_e + off2];

        // prefetch next edge's snd/nh (independent of this iteration's chain)
        if (i + 1 < cnt) {
            snd_n = snd_perm[idx + 1];
            nh_n  = *(const float4*)(nh_perm + (size_t)(idx + 1) * 4);
        }

        float su = s_in[(size_t)snd * NC + c];
        float v0 = v_in[(size_t)snd * 96 + c];
        float v1 = v_in[(size_t)snd * 96 + 32 + c];
        float v2 = v_in[(size_t)snd * 96 + 64 + c];
        float ndv = nh.x * v0;
        ndv = fmaf(nh.y, v1, ndv);
        ndv = fmaf(nh.z, v2, ndv);

        float sSel = half ? ndv : su;          // path1 vs path0 multiplier
        accS = fmaf(d0, sSel, accS);
        float scale = half ? d1 : d1 * su;     // path3: w3 ; path2: w2*su
        float f0 = half ? v0 : nh.x;
        float f1 = half ? v1 : nh.y;
        float f2 = half ? v2 : nh.z;
        aVa0 = fmaf(scale, f0, aVa0);
        aVa1 = fmaf(scale, f1, aVa1);
        aVa2 = fmaf(scale, f2, aVa2);
        float m4 = half ? 0.f : d2f;           // path4 only on half0
        aVb0 = fmaf(m4, fmaf(nh.x, ndv, -v0 * (1.f / 3.f)), aVb0);
        aVb1 = fmaf(m4, fmaf(nh.y, ndv, -v1 * (1.f / 3.f)), aVb1);
        aVb2 = fmaf(m4, fmaf(nh.z, ndv, -v2 * (1.f / 3.f)), aVb2);
    }

    agg_s[(size_t)n * 64 + lane] = accS;
    float* av = agg_v + (size_t)n * 288;
    if (half == 0) {
        av[c * 3 + 0] = aVa0; av[c * 3 + 1] = aVa1; av[c * 3 + 2] = aVa2;                      // path2
        av[(64 + c) * 3 + 0] = aVb0; av[(64 + c) * 3 + 1] = aVb1; av[(64 + c) * 3 + 2] = aVb2; // path4
    } else {
        av[(32 + c) * 3 + 0] = aVa0; av[(32 + c) * 3 + 1] = aVa1; av[(32 + c) * 3 + 2] = aVa2; // path3
    }
}

// ---------------------------------------------------------------- fallback gather (Round-2)
__global__ __launch_bounds__(512) void gather_kernel(
    const float* __restrict__ rb, const float* __restrict__ nhat4,
    const int* __restrict__ senders, const int* __restrict__ edge_order,
    const int* __restrict__ rowstart, const int* __restrict__ deg,
    const float* __restrict__ s_in, const float* __restrict__ v_in,
    const float* __restrict__ w1, const float* __restrict__ w2, const float* __restrict__ w3,
    float* __restrict__ agg_s, float* __restrict__ agg_v)
{
    __shared__ float sW2[NH * NH];
    __shared__ float sW3[NH * 160];
    for (int i = threadIdx.x; i < NH * NH;  i += 512) sW2[i] = w2[i];
    for (int i = threadIdx.x; i < NH * 160; i += 512) sW3[i] = w3[i];
    __syncthreads();
    int lane = threadIdx.x & 63;
    int wid  = threadIdx.x >> 6;
    int n = blockIdx.x * 8 + wid;
    if (n >= NNODES) return;
    int c = lane & 31;
    int half = lane >> 5;
    float w1r[8];
    #pragma unroll
    for (int b = 0; b < 8; ++b) w1r[b] = w1[b * NH + lane];
    float accS = 0.f;
    float aVa0 = 0.f, aVa1 = 0.f, aVa2 = 0.f;
    float aVb0 = 0.f, aVb1 = 0.f, aVb2 = 0.f;
    int start = rowstart[n];
    int cnt   = deg[n];
    for (int i = 0; i < cnt; ++i) {
        int e   = edge_order[start + i];
        int snd = senders[e];
        float4 nh  = *(const float4*)(nhat4 + (size_t)e * 4);
        float4 rba = *(const float4*)(rb + (size_t)e * 8);
        float4 rbb = *(const float4*)(rb + (size_t)e * 8 + 4);
        float h1v;
        h1v = rba.x * w1r[0];
        h1v = fmaf(rba.y, w1r[1], h1v);
        h1v = fmaf(rba.z, w1r[2], h1v);
        h1v = fmaf(rba.w, w1r[3], h1v);
        h1v = fmaf(rbb.x, w1r[4], h1v);
        h1v = fmaf(rbb.y, w1r[5], h1v);
        h1v = fmaf(rbb.z, w1r[6], h1v);
        h1v = fmaf(rbb.w, w1r[7], h1v);
        h1v = silu_f(h1v);
        float a0 = 0.f, a1 = 0.f;
        #pragma unroll
        for (int k = 0; k < NH; k += 2) {
            a0 = fmaf(rdlane(h1v, k),     sW2[k * NH + lane],       a0);
            a1 = fmaf(rdlane(h1v, k + 1), sW2[(k + 1) * NH + lane], a1);
        }
        float h2v = silu_f(a0 + a1);
        float d0a = 0.f, d0b = 0.f, d1a = 0.f, d1b = 0.f, d2a = 0.f, d2b = 0.f;
        #pragma unroll
        for (int k = 0; k < NH; k += 2) {
            float hA = rdlane(h2v, k);
            float hB = rdlane(h2v, k + 1);
            d0a = fmaf(hA, sW3[k * 160 + lane],            d0a);
            d1a = fmaf(hA, sW3[k * 160 + 64 + lane],       d1a);
            d2a = fmaf(hA, sW3[k * 160 + 128 + c],         d2a);
            d0b = fmaf(hB, sW3[(k + 1) * 160 + lane],      d0b);
            d1b = fmaf(hB, sW3[(k + 1) * 160 + 64 + lane], d1b);
            d2b = fmaf(hB, sW3[(k + 1) * 160 + 128 + c],   d2b);
        }
        float d0 = d0a + d0b;
        float d1 = d1a + d1b;
        float d2 = d2a + d2b;
        float su = s_in[(size_t)snd * NC + c];
        float v0 = v_in[(size_t)snd * 96 + c];
        float v1 = v_in[(size_t)snd * 96 + 32 + c];
        float v2 = v_in[(size_t)snd * 96 + 64 + c];
        float ndv = nh.x * v0;
        ndv = fmaf(nh.y, v1, ndv);
        ndv = fmaf(nh.z, v2, ndv);
        float sSel = half ? ndv : su;
        accS = fmaf(d0, sSel, accS);
        float scale = half ? d1 : d1 * su;
        float f0 = half ? v0 : nh.x;
        float f1 = half ? v1 : nh.y;
        float f2 = half ? v2 : nh.z;
        aVa0 = fmaf(scale, f0, aVa0);
        aVa1 = fmaf(scale, f1, aVa1);
        aVa2 = fmaf(scale, f2, aVa2);
        float m4 = half ? 0.f : d2;
        aVb0 = fmaf(m4, fmaf(nh.x, ndv, -v0 * (1.f / 3.f)), aVb0);
        aVb1 = fmaf(m4, fmaf(nh.y, ndv, -v1 * (1.f / 3.f)), aVb1);
        aVb2 = fmaf(m4, fmaf(nh.z, ndv, -v2 * (1.f / 3.f)), aVb2);
    }
    agg_s[(size_t)n * 64 + lane] = accS;
    float* av = agg_v + (size_t)n * 288;
    if (half == 0) {
        av[c * 3 + 0] = aVa0; av[c * 3 + 1] = aVa1; av[c * 3 + 2] = aVa2;
        av[(64 + c) * 3 + 0] = aVb0; av[(64 + c) * 3 + 1] = aVb1; av[(64 + c) * 3 + 2] = aVb2;
    } else {
        av[(32 + c) * 3 + 0] = aVa0; av[(32 + c) * 3 + 1] = aVa1; av[(32 + c) * 3 + 2] = aVa2;
    }
}

// ---------------------------------------------------------------- node update (v2)
__global__ __launch_bounds__(256) void node_kernel(
    const int* __restrict__ specie,
    const float* __restrict__ agg_s, const float* __restrict__ agg_v,
    const float* __restrict__ s_in,  const float* __restrict__ v_in,
    const float* __restrict__ wls,   // [64][64]
    const float* __restrict__ wlv,   // [96][32]
    const float* __restrict__ wscs,  // [5][32][64]
    const float* __restrict__ wscv,  // [5][32][32]
    float* __restrict__ s_out, float* __restrict__ v_out)
{
    __shared__ float sAV[4][288];
    __shared__ float sVO[4][96];

    int lane = threadIdx.x & 63;
    int wid  = threadIdx.x >> 6;
    int n = blockIdx.x * 4 + wid;
    if (n >= NNODES) return;
    int sp = specie[n];

    const float* av = agg_v + (size_t)n * 288;
    sAV[wid][lane]       = av[lane];
    sAV[wid][64 + lane]  = av[64 + lane];
    sAV[wid][128 + lane] = av[128 + lane];
    sAV[wid][192 + lane] = av[192 + lane];
    if (lane < 32) sAV[wid][256 + lane] = av[256 + lane];
    const float* vo = v_in + (size_t)n * 96;
    if (lane < 32) {
        sVO[wid][lane]      = vo[lane];
        sVO[wid][32 + lane] = vo[32 + lane];
        sVO[wid][64 + lane] = vo[64 + lane];
    }

    float asv = agg_s[(size_t)n * 64 + lane];
    float sv  = s_in[(size_t)n * 32 + (lane & 31)];

    __syncthreads();

    float sg = 0.f;
    #pragma unroll
    for (int j = 0; j < 64; ++j)
        sg = fmaf(rdlane(asv, j), wls[j * 64 + lane], sg);
    sg *= INV_AVG;
    const float* ws = wscs + (size_t)sp * 32 * 64;
    #pragma unroll
    for (int j = 0; j < 32; ++j)
        sg = fmaf(rdlane(sv, j), ws[j * 64 + lane], sg);
    float act  = silu_f(sg);
    float gate = __shfl(act, (lane & 31) + 32);

    int c = lane & 31;
    int h = lane >> 5;
    float vn1 = 0.f, vn2 = 0.f;
    #pragma unroll
    for (int p = 0; p < 96; ++p) {
        float w = wlv[p * 32 + c];
        vn1 = fmaf(sAV[wid][3 * p + h], w, vn1);
        vn2 = fmaf(sAV[wid][3 * p + 2], w, vn2);
    }
    vn1 *= INV_AVG; vn2 *= INV_AVG;
    const float* wv = wscv + (size_t)sp * 32 * 32;
    #pragma unroll
    for (int j = 0; j < 32; ++j) {
        float w = wv[j * 32 + c];
        vn1 = fmaf(sVO[wid][h * 32 + j], w, vn1);
        vn2 = fmaf(sVO[wid][64 + j],     w, vn2);
    }

    if (lane < 32) s_out[(size_t)n * 32 + lane] = act;
    v_out[(size_t)n * 96 + h * 32 + c] = gate * vn1;
    if (h == 0) v_out[(size_t)n * 96 + 64 + c] = gate * vn2;
}

// ---------------------------------------------------------------- output head
__global__ void out_kernel(const float* __restrict__ s,
                           const float* __restrict__ w1,  // [32][16]
                           const float* __restrict__ w2,  // [16][1]
                           float* __restrict__ out) {
    int n = blockIdx.x * blockDim.x + threadIdx.x;
    if (n >= NNODES) return;
    float sv[NC];
    #pragma unroll
    for (int c = 0; c < NC; ++c) sv[c] = s[(size_t)n * NC + c];
    float e = 0.f;
    #pragma unroll
    for (int j = 0; j < 16; ++j) {
        float tj = 0.f;
        #pragma unroll
        for (int c = 0; c < NC; ++c) tj += sv[c] * w1[c * 16 + j];
        e += tj * w2[j];
    }
    out[n] = e;
}

// ---------------------------------------------------------------- launcher
extern "C" void kernel_launch(void* const* d_in, const int* in_sizes, int n_in,
                              void* d_out, int out_size, void* d_ws, size_t ws_size,
                              hipStream_t stream) {
    const float* vectors   = (const float*)d_in[0];
    const int*   specie    = (const int*)  d_in[1];
    const int*   senders   = (const int*)  d_in[2];
    const int*   receivers = (const int*)  d_in[3];
    const float* emb       = (const float*)d_in[4];
    const float* w_rad1    = (const float*)d_in[5];
    const float* w_rad2    = (const float*)d_in[6];
    const float* w_rad_out = (const float*)d_in[7];
    const float* w_lin_s   = (const float*)d_in[8];
    const float* w_lin_v   = (const float*)d_in[9];
    const float* w_sc_s    = (const float*)d_in[10];
    const float* w_sc_v    = (const float*)d_in[11];
    const float* w_out1    = (const float*)d_in[12];
    const float* w_out2    = (const float*)d_in[13];

    char* base = (char*)d_ws;
    size_t off = 0;
    auto alloc = [&](size_t bytes) { char* q = base + off; off += (bytes + 255) & ~(size_t)255; return q; };

    float* nhat4 = (float*)alloc((size_t)NEDGES * 4 * 4);
    float* rb    = (float*)alloc((size_t)NEDGES * 8 * 4);
    float* s_a   = (float*)alloc((size_t)NNODES * NC * 4);
    float* v_a   = (float*)alloc((size_t)NNODES * NC * 3 * 4);
    float* s_b   = (float*)alloc((size_t)NNODES * NC * 4);
    float* v_b   = (float*)alloc((size_t)NNODES * NC * 3 * 4);
    float* aggs  = (float*)alloc((size_t)NNODES * 2 * NC * 4);
    float* aggv  = (float*)alloc((size_t)NNODES * 3 * NC * 3 * 4);
    int* deg        = (int*)alloc((size_t)NNODES * 4);
    int* rowstart   = (int*)alloc((size_t)(NNODES + 4) * 4);
    int* cursor     = (int*)alloc((size_t)NNODES * 4);
    int* edge_order = (int*)alloc((size_t)NEDGES * 4);
    // big-path extras
    float*    nh_perm  = (float*)alloc((size_t)NEDGES * 4 * 4);
    int*      snd_perm = (int*)alloc((size_t)NEDGES * 4);
    float*    w1t      = (float*)alloc((size_t)NL * 64 * 8 * 4);
    _Float16* w2f      = (_Float16*)alloc((size_t)NL * 2 * 4 * 64 * 8 * 2);
    _Float16* w3f      = (_Float16*)alloc((size_t)NL * 2 * 10 * 64 * 8 * 2);
    _Float16* wgt16    = (_Float16*)alloc((size_t)NEDGES * 160 * 2);
    bool big = (off <= ws_size);

    geom_kernel<<<(NEDGES + 255) / 256, 256, 0, stream>>>(vectors, nhat4, rb);
    (void)hipMemsetAsync(deg, 0, NNODES * sizeof(int), stream);
    count_kernel<<<(NEDGES + 255) / 256, 256, 0, stream>>>(receivers, deg);
    scan_kernel<<<1, 256, 0, stream>>>(deg, rowstart);
    copy_cursor_kernel<<<(NNODES + 255) / 256, 256, 0, stream>>>(rowstart, cursor);
    fill_kernel<<<(NEDGES + 255) / 256, 256, 0, stream>>>(receivers, cursor, edge_order);
    if (big) {
        perm_kernel<<<(NEDGES + 255) / 256, 256, 0, stream>>>(
            edge_order, senders, nhat4, nh_perm, snd_perm);
        int prep_n = NL * 64 * 8 + NL * 2 * 4 * 64 * 8 + NL * 2 * 10 * 64 * 8;
        prepw_kernel<<<(prep_n + 255) / 256, 256, 0, stream>>>(
            w_rad1, w_rad2, w_rad_out, w1t, w2f, w3f);
    }

    init_kernel<<<(NNODES * NC + 255) / 256, 256, 0, stream>>>(specie, emb, s_a);
    (void)hipMemsetAsync(v_a, 0, (size_t)NNODES * NC * 3 * sizeof(float), stream);

    float* si = s_a; float* vi = v_a; float* so = s_b; float* vo = v_b;
    for (int l = 0; l < NL; ++l) {
        if (big) {
            mlpm_kernel<<<NEDGES / 64, 256, 0, stream>>>(
                rb, edge_order,
                w1t + (size_t)l * 512,
                w2f + (size_t)l * 4096,
                w3f + (size_t)l * 10240,
                wgt16);
            gather_tp_kernel<<<NNODES / 8, 512, 0, stream>>>(
                wgt16, nh_perm, snd_perm, rowstart, deg, si, vi, aggs, aggv);
        } else {
            gather_kernel<<<NNODES / 8, 512, 0, stream>>>(
                rb, nhat4, senders, edge_order, rowstart, deg, si, vi,
                w_rad1 + (size_t)l * NBASIS * NH,
                w_rad2 + (size_t)l * NH * NH,
                w_rad_out + (size_t)l * NH * 160,
                aggs, aggv);
        }
        node_kernel<<<(NNODES + 3) / 4, 256, 0, stream>>>(
            specie, aggs, aggv, si, vi,
            w_lin_s + (size_t)l * 64 * 64,
            w_lin_v + (size_t)l * 96 * 32,
            w_sc_s + (size_t)l * NSPEC * NC * 64,
            w_sc_v + (size_t)l * NSPEC * NC * NC,
            so, vo);
        float* ts = si; si = so; so = ts;
        float* tv = vi; vi = vo; vo = tv;
    }

    out_kernel<<<(NNODES + 255) / 256, 256, 0, stream>>>(si, w_out1, w_out2, (float*)d_out);
}